// Round 16
// baseline (215.520 us; speedup 1.0000x reference)
//
#include <hip/hip_runtime.h>
#include <hip/hip_bf16.h>
#include <math.h>

// OptimizeSNR R16: direct-from-global Toeplitz-swap MFMA. No LDS, no barriers.
//   out[t0+16m+n] = sum_p A[m,p]*B[p,n]
//   A[m,p] = x[t0-64+16m+p]  (per-lane 10 float4 loads straight from global;
//            all 64 lanes share one row's 2.2 KB window -> L1-resident)
//   B[p,n] = k[p-n]          (k-Toeplitz, VGPRs)
//   Depth-2 counted-vmcnt register prefetch; cvt_pk in-reg; 1 wave = 1 row seg.
constexpr int Bc = 8, Cc = 128, Lc = 32768, Kc = 129, PAD = 64;

constexpr int MLEN = 256;              // outputs per chunk (one 16x16 tile)
constexpr int T    = 16;               // chunks per wave
constexpr int NSEG = Lc / (MLEN * T);  // 8 segments per row
constexpr int WPB  = 4;                // waves per block
constexpr int THREADS = 64 * WPB;      // 256
constexpr int LASTCW  = Lc / MLEN - 1; // 127

typedef __attribute__((ext_vector_type(8))) short short8;
typedef __attribute__((ext_vector_type(4))) float floatx4;

#define WAITVM(N) do { asm volatile("s_waitcnt vmcnt(" #N ")" ::: "memory"); \
                       __builtin_amdgcn_sched_barrier(0); } while (0)

__device__ __forceinline__ unsigned short f2bf(float f) {
    return __builtin_bit_cast(unsigned short, __float2bfloat16(f));
}

__device__ __forceinline__ short8 cvt8(const float4& a, const float4& b) {
    __hip_bfloat162 p0 = __float22bfloat162_rn(make_float2(a.x, a.y));
    __hip_bfloat162 p1 = __float22bfloat162_rn(make_float2(a.z, a.w));
    __hip_bfloat162 p2 = __float22bfloat162_rn(make_float2(b.x, b.y));
    __hip_bfloat162 p3 = __float22bfloat162_rn(make_float2(b.z, b.w));
    ushort2 u0, u1, u2, u3;
    __builtin_memcpy(&u0, &p0, 4);
    __builtin_memcpy(&u1, &p1, 4);
    __builtin_memcpy(&u2, &p2, 4);
    __builtin_memcpy(&u3, &p3, 4);
    short8 r;
    r[0] = (short)u0.x; r[1] = (short)u0.y;
    r[2] = (short)u1.x; r[3] = (short)u1.y;
    r[4] = (short)u2.x; r[5] = (short)u2.y;
    r[6] = (short)u3.x; r[7] = (short)u3.y;
    return r;
}

// Per-channel complex scale: sc = nm*cos(atan(a)), ss = nm*sin(atan(a))
__global__ void scale_kernel(const float* __restrict__ wm,
                             const float* __restrict__ wa,
                             float* __restrict__ ws, int C, float batchf) {
    int c = threadIdx.x;
    if (c >= C) return;
    float m = -1e30f;
    for (int i = 0; i < C; ++i) m = fmaxf(m, wm[i]);
    float s = 0.f;
    for (int i = 0; i < C; ++i) s += expf(wm[i] - m);
    float nm = batchf * expf(wm[c] - m) / s;
    float a = wa[c];
    float inv = rsqrtf(1.f + a * a);
    ws[2 * c]     = nm * inv;       // sc
    ws[2 * c + 1] = nm * a * inv;   // ss
}

__global__ __launch_bounds__(THREADS, 3)
void mf_kernel(const float* __restrict__ x,
               const float* __restrict__ kr,
               const float* __restrict__ ki,
               const float* __restrict__ sc_ss,
               float* __restrict__ out, int interleaved) {
    const int seg = blockIdx.x;            // 8 segments
    const int rg  = blockIdx.y;            // 256 row groups (4 rows)
    const int tid = threadIdx.x;
    const int lane= tid & 63;
    const int wv  = tid >> 6;              // wave 0..3
    const int fh  = lane >> 4;             // 0..3
    const int fn  = lane & 15;             // 0..15
    const int loff= 16 * fn + 8 * fh;      // lane's float offset in window

    const int row = rg * WPB + wv;         // this wave's row (0..1023)
    const int cw0 = seg * T;               // first chunk

    // ---- B fragments (k-Toeplitz): B_d[kl][n] = k[32d + kl - n]; lane: n=fn, kl=8*fh+e
    short8 br[5], bi[5];
    #pragma unroll
    for (int d = 0; d < 5; ++d) {
        #pragma unroll
        for (int e = 0; e < 8; ++e) {
            int idx = 32 * d + 8 * fh + e - fn;
            bool ok = (idx >= 0) && (idx < Kc);
            br[d][e] = (short)f2bf(ok ? kr[idx] : 0.f);
            bi[d][e] = (short)f2bf(ok ? ki[idx] : 0.f);
        }
    }

    const int ch = row & (Cc - 1);
    const float scv = sc_ss[2 * ch];
    const float ssv = sc_ss[2 * ch + 1];

    const float* __restrict__ xrow = x + (size_t)row * Lc;

    float4 F[2][10];

    // Issue chunk cw's 10 loads into F[buf]. Edge chunks clamp addresses
    // (same instruction count -> uniform vmcnt bookkeeping); garbage lanes
    // are zeroed post-cvt.
    auto ISSUE = [&](int cw, int buf) {
        const int g0 = cw * MLEN - PAD + loff;
        if (cw == 0 || cw == LASTCW) {
            #pragma unroll
            for (int d = 0; d < 5; ++d) {
                int ga = min(max(g0 + 32 * d, 0), Lc - 4);
                int gb = min(max(g0 + 32 * d + 4, 0), Lc - 4);
                F[buf][2 * d]     = *reinterpret_cast<const float4*>(xrow + ga);
                F[buf][2 * d + 1] = *reinterpret_cast<const float4*>(xrow + gb);
            }
        } else {
            #pragma unroll
            for (int d = 0; d < 5; ++d) {
                F[buf][2 * d]     = *reinterpret_cast<const float4*>(xrow + g0 + 32 * d);
                F[buf][2 * d + 1] = *reinterpret_cast<const float4*>(xrow + g0 + 32 * d + 4);
            }
        }
    };

    // ---- prologue: prime chunks cw0, cw0+1 ----
    ISSUE(cw0, 0);
    ISSUE(cw0 + 1, 1);

    #pragma unroll
    for (int c = 0; c < T; ++c) {
        const int cw  = cw0 + c;
        const int buf = c & 1;

        // wait for chunk c's loads (exact counted; stores included)
        if (c == 0)          WAITVM(10);
        else if (c == 1)     WAITVM(14);
        else if (c == T - 1) WAITVM(8);
        else                 WAITVM(18);

        // convert to bf16 A-fragments in-register
        short8 a[5];
        #pragma unroll
        for (int d = 0; d < 5; ++d)
            a[d] = cvt8(F[buf][2 * d], F[buf][2 * d + 1]);

        // edge fix: zero elements whose source position fell outside [0, Lc)
        if (cw == 0) {
            #pragma unroll
            for (int d = 0; d < 2; ++d)        // 32d >= 64 for d>=2: always valid
                #pragma unroll
                for (int e = 0; e < 8; ++e)
                    if (loff + 32 * d + e < 64) a[d][e] = 0;
        } else if (cw == LASTCW) {
            #pragma unroll
            for (int d = 2; d < 5; ++d)        // d<2: max pos 32447+39 < Lc: valid
                #pragma unroll
                for (int e = 0; e < 8; ++e)
                    if (loff + 32 * d + e >= 320) a[d][e] = 0;
        }

        // issue chunk c+2's loads before the MFMAs (overwrites F[buf], now dead)
        if (c + 2 < T) ISSUE(cw0 + c + 2, buf);

        floatx4 cr = {0.f, 0.f, 0.f, 0.f};
        floatx4 ci = {0.f, 0.f, 0.f, 0.f};
        #pragma unroll
        for (int d = 0; d < 5; ++d) {
            cr = __builtin_amdgcn_mfma_f32_16x16x32_bf16(a[d], br[d], cr, 0, 0, 0);
            ci = __builtin_amdgcn_mfma_f32_16x16x32_bf16(a[d], bi[d], ci, 0, 0, 0);
        }

        // D[m=4*fh+r][n=fn]; output pos = cw*256 + 16m + n
        if (!interleaved) {
            float* op = out + (size_t)row * Lc + cw * MLEN + 64 * fh + fn;
            #pragma unroll
            for (int r = 0; r < 4; ++r)
                op[16 * r] = scv * cr[r] - ssv * ci[r];
        } else {
            float2* op = reinterpret_cast<float2*>(out) +
                         ((size_t)row * Lc + cw * MLEN + 64 * fh + fn);
            #pragma unroll
            for (int r = 0; r < 4; ++r)
                op[16 * r] = make_float2(scv * cr[r] - ssv * ci[r],
                                         -scv * ci[r] - ssv * cr[r]);
        }
    }
}

extern "C" void kernel_launch(void* const* d_in, const int* in_sizes, int n_in,
                              void* d_out, int out_size, void* d_ws, size_t ws_size,
                              hipStream_t stream) {
    const float* x  = (const float*)d_in[0];
    const float* wm = (const float*)d_in[1];
    const float* wa = (const float*)d_in[2];
    const float* kr = (const float*)d_in[3];
    const float* ki = (const float*)d_in[4];
    float* out = (float*)d_out;
    float* ws  = (float*)d_ws;

    const int C = in_sizes[1];  // 128
    const long long N = (long long)Bc * Cc * Lc;
    const int interleaved = (out_size == 2 * N) ? 1 : 0;

    hipLaunchKernelGGL(scale_kernel, dim3(1), dim3(C), 0, stream,
                       wm, wa, ws, C, (float)Bc);

    dim3 grid(NSEG, (Bc * Cc) / WPB);   // 8 x 256 = 2048 blocks
    hipLaunchKernelGGL(mf_kernel, grid, dim3(THREADS), 0, stream,
                       x, kr, ki, ws, out, interleaved);
}

// Round 17
// 142.200 us; speedup vs baseline: 1.5156x; 1.5156x over previous
//
#include <hip/hip_runtime.h>
#include <hip/hip_bf16.h>
#include <math.h>

// OptimizeSNR R17: Toeplitz-swap MFMA, one-LDS-trip, swizzled-source DMA.
//   out[t0+16m+n] = sum_p A[m,p]*B[p,n]
//   A[m,p] = x[t0-64+16m+p]  staged fp32 in wave-private LDS via
//            global_load_lds with PERMUTED source (instr0: lane L <- x[s0+8L],
//            instr1: lane L <- x[s0+8L+4]) so that fragment (fn,fh,d) is two
//            contiguous float4s at LDS floats {8fn+4fh+16d, 256+8fn+4fh+16d}.
//   B[p,n] = k[p-n]  (k-Toeplitz, VGPRs). cvt fp32->bf16 in-reg after ds_read.
//   Depth-3 counted-vmcnt pipeline, zero barriers, float4 stores via LDS bounce.
constexpr int Bc = 8, Cc = 128, Lc = 32768, Kc = 129, PAD = 64;

constexpr int MLEN = 256;              // outputs per chunk (one 16x16 tile)
constexpr int T    = 16;               // chunks per wave
constexpr int NSEG = Lc / (MLEN * T);  // 8 segments per row
constexpr int WPB  = 4;                // waves per block
constexpr int THREADS = 64 * WPB;      // 256
constexpr int LASTCW  = Lc / MLEN - 1; // 127

typedef __attribute__((ext_vector_type(8))) short short8;
typedef __attribute__((ext_vector_type(4))) float floatx4;

#define WAITVM(N) do { asm volatile("s_waitcnt vmcnt(" #N ")" ::: "memory"); \
                       __builtin_amdgcn_sched_barrier(0); } while (0)
#define WAITLG()  do { asm volatile("s_waitcnt lgkmcnt(0)" ::: "memory"); \
                       __builtin_amdgcn_sched_barrier(0); } while (0)

__device__ __forceinline__ unsigned short f2bf(float f) {
    return __builtin_bit_cast(unsigned short, __float2bfloat16(f));
}

__device__ __forceinline__ short8 cvt8(const float4& a, const float4& b) {
    __hip_bfloat162 p0 = __float22bfloat162_rn(make_float2(a.x, a.y));
    __hip_bfloat162 p1 = __float22bfloat162_rn(make_float2(a.z, a.w));
    __hip_bfloat162 p2 = __float22bfloat162_rn(make_float2(b.x, b.y));
    __hip_bfloat162 p3 = __float22bfloat162_rn(make_float2(b.z, b.w));
    ushort2 u0, u1, u2, u3;
    __builtin_memcpy(&u0, &p0, 4);
    __builtin_memcpy(&u1, &p1, 4);
    __builtin_memcpy(&u2, &p2, 4);
    __builtin_memcpy(&u3, &p3, 4);
    short8 r;
    r[0] = (short)u0.x; r[1] = (short)u0.y;
    r[2] = (short)u1.x; r[3] = (short)u1.y;
    r[4] = (short)u2.x; r[5] = (short)u2.y;
    r[6] = (short)u3.x; r[7] = (short)u3.y;
    return r;
}

__device__ __forceinline__ void gload_lds16(const float* g, void* l) {
    auto gp = (const __attribute__((address_space(1))) void*)g;
    auto lp = (__attribute__((address_space(3))) void*)l;
    __builtin_amdgcn_global_load_lds(gp, lp, 16, 0, 0);
}

// Per-channel complex scale: sc = nm*cos(atan(a)), ss = nm*sin(atan(a))
__global__ void scale_kernel(const float* __restrict__ wm,
                             const float* __restrict__ wa,
                             float* __restrict__ ws, int C, float batchf) {
    int c = threadIdx.x;
    if (c >= C) return;
    float m = -1e30f;
    for (int i = 0; i < C; ++i) m = fmaxf(m, wm[i]);
    float s = 0.f;
    for (int i = 0; i < C; ++i) s += expf(wm[i] - m);
    float nm = batchf * expf(wm[c] - m) / s;
    float a = wa[c];
    float inv = rsqrtf(1.f + a * a);
    ws[2 * c]     = nm * inv;       // sc
    ws[2 * c + 1] = nm * a * inv;   // ss
}

__global__ __launch_bounds__(THREADS, 5)
void mf_kernel(const float* __restrict__ x,
               const float* __restrict__ kr,
               const float* __restrict__ ki,
               const float* __restrict__ sc_ss,
               float* __restrict__ out, int interleaved) {
    __shared__ __align__(16) float lf[WPB][3][512];   // 24 KB: depth-3 fp32 stage
    __shared__ __align__(16) float lo[WPB][256];      // 4 KB: output bounce

    const int seg = blockIdx.x;            // 8 segments
    const int rg  = blockIdx.y;            // 256 row groups (4 rows)
    const int tid = threadIdx.x;
    const int lane= tid & 63;
    const int wv  = tid >> 6;              // wave 0..3
    const int fh  = lane >> 4;             // 0..3
    const int fn  = lane & 15;             // 0..15
    const int loff= 16 * fn + 8 * fh;      // lane's window float offset

    const int row = rg * WPB + wv;         // this wave's row (0..1023)
    const int cw0 = seg * T;               // first chunk

    // ---- B fragments (k-Toeplitz): B_d[kl][n] = k[32d + kl - n]; lane: n=fn, kl=8*fh+e
    short8 br[5], bi[5];
    #pragma unroll
    for (int d = 0; d < 5; ++d) {
        #pragma unroll
        for (int e = 0; e < 8; ++e) {
            int idx = 32 * d + 8 * fh + e - fn;
            bool ok = (idx >= 0) && (idx < Kc);
            br[d][e] = (short)f2bf(ok ? kr[idx] : 0.f);
            bi[d][e] = (short)f2bf(ok ? ki[idx] : 0.f);
        }
    }

    const int ch = row & (Cc - 1);
    const float scv = sc_ss[2 * ch];
    const float ssv = sc_ss[2 * ch + 1];

    const float* __restrict__ xrow = x + (size_t)row * Lc;

    // DMA with permuted per-lane source; clamped (edge lanes deliver garbage
    // only to window positions that are zeroed at use).
    auto DMA = [&](int cw, int dep) {
        const int s0 = cw * MLEN - PAD;
        const int g  = s0 + 8 * lane;
        const int ga = min(max(g, 0), Lc - 4);
        const int gb = min(max(g + 4, 0), Lc - 4);
        gload_lds16(xrow + ga, (char*)&lf[wv][dep][0]);
        gload_lds16(xrow + gb, (char*)&lf[wv][dep][256]);
    };

    // ---- prologue: prime chunks cw0..cw0+2 ----
    DMA(cw0, 0);
    DMA(cw0 + 1, 1);
    DMA(cw0 + 2, 2);

    #pragma unroll
    for (int c = 0; c < T; ++c) {
        const int cw  = cw0 + c;
        const int dep = c % 3;

        // wait chunk c's 2 DMA ops (exact counted; 1 store + 2 DMA per later iter)
        if (c == 0)          WAITVM(4);
        else if (c == 1)     WAITVM(5);
        else if (c == T - 2) WAITVM(4);
        else if (c == T - 1) WAITVM(2);
        else                 WAITVM(6);

        // fragments: 2 ds_read_b128 each, cvt in-reg
        const float* lwp = &lf[wv][dep][0];
        short8 a[5];
        #pragma unroll
        for (int d = 0; d < 5; ++d) {
            float4 fa = *reinterpret_cast<const float4*>(lwp + 8 * fn + 4 * fh + 16 * d);
            float4 fb = *reinterpret_cast<const float4*>(lwp + 256 + 8 * fn + 4 * fh + 16 * d);
            a[d] = cvt8(fa, fb);
        }

        // edge fix: zero elements whose source position fell outside [0, Lc)
        if (cw == 0) {
            #pragma unroll
            for (int d = 0; d < 2; ++d)
                #pragma unroll
                for (int e = 0; e < 8; ++e)
                    if (loff + 32 * d + e < 64) a[d][e] = 0;
        } else if (cw == LASTCW) {
            #pragma unroll
            for (int d = 2; d < 5; ++d)
                #pragma unroll
                for (int e = 0; e < 8; ++e)
                    if (loff + 32 * d + e >= 320) a[d][e] = 0;
        }

        floatx4 cr = {0.f, 0.f, 0.f, 0.f};
        floatx4 ci = {0.f, 0.f, 0.f, 0.f};
        #pragma unroll
        for (int d = 0; d < 5; ++d) {
            cr = __builtin_amdgcn_mfma_f32_16x16x32_bf16(a[d], br[d], cr, 0, 0, 0);
            ci = __builtin_amdgcn_mfma_f32_16x16x32_bf16(a[d], bi[d], ci, 0, 0, 0);
        }

        // D[m=4*fh+r][n=fn]; output pos = cw*256 + 64*fh + 16*r + fn
        if (!interleaved) {
            // bounce through LDS -> one contiguous dwordx4 store per lane
            #pragma unroll
            for (int r = 0; r < 4; ++r)
                lo[wv][64 * fh + 16 * r + fn] = scv * cr[r] - ssv * ci[r];
            WAITLG();
            float4 ov = *reinterpret_cast<const float4*>(&lo[wv][4 * lane]);
            WAITLG();
            *reinterpret_cast<float4*>(out + (size_t)row * Lc + cw * MLEN + 4 * lane) = ov;
        } else {
            float2* op = reinterpret_cast<float2*>(out) +
                         ((size_t)row * Lc + cw * MLEN + 64 * fh + fn);
            #pragma unroll
            for (int r = 0; r < 4; ++r)
                op[16 * r] = make_float2(scv * cr[r] - ssv * ci[r],
                                         -scv * ci[r] - ssv * cr[r]);
        }

        // issue chunk c+3 (reuses this dep's buffer; all lgkm drained above)
        if (c + 3 < T) DMA(cw0 + c + 3, dep);
    }
}

extern "C" void kernel_launch(void* const* d_in, const int* in_sizes, int n_in,
                              void* d_out, int out_size, void* d_ws, size_t ws_size,
                              hipStream_t stream) {
    const float* x  = (const float*)d_in[0];
    const float* wm = (const float*)d_in[1];
    const float* wa = (const float*)d_in[2];
    const float* kr = (const float*)d_in[3];
    const float* ki = (const float*)d_in[4];
    float* out = (float*)d_out;
    float* ws  = (float*)d_ws;

    const int C = in_sizes[1];  // 128
    const long long N = (long long)Bc * Cc * Lc;
    const int interleaved = (out_size == 2 * N) ? 1 : 0;

    hipLaunchKernelGGL(scale_kernel, dim3(1), dim3(C), 0, stream,
                       wm, wa, ws, C, (float)Bc);

    dim3 grid(NSEG, (Bc * Cc) / WPB);   // 8 x 256 = 2048 blocks
    hipLaunchKernelGGL(mf_kernel, grid, dim3(THREADS), 0, stream,
                       x, kr, ki, ws, out, interleaved);
}

// Round 19
// 108.105 us; speedup vs baseline: 1.9936x; 1.3154x over previous
//
#include <hip/hip_runtime.h>
#include <hip/hip_bf16.h>
#include <math.h>

// OptimizeSNR R19: 32x32x16 MFMA Toeplitz-swap, wave-autonomous, zero barriers.
// R18 + swizzle fix: BOTH granules of each A-fragment get independently
// swizzled LDS addresses (G+1's slot is swz(G)^1, not swz(G)+1).
constexpr int Bc = 8, Cc = 128, Lc = 32768, Kc = 129;

constexpr int TILE = 1024;             // outputs per tile (one 32x32 MFMA tile)
constexpr int T    = 4;                // tiles per wave
constexpr int NSEG = Lc / (TILE * T);  // 8 segments per row
constexpr int WPB  = 4;                // waves per block
constexpr int THREADS = 64 * WPB;      // 256
constexpr int LASTTILE = Lc / TILE - 1; // 31

typedef __attribute__((ext_vector_type(8)))  short short8;
typedef __attribute__((ext_vector_type(16))) float floatx16;

#define WAITVM(N) do { asm volatile("s_waitcnt vmcnt(" #N ")" ::: "memory"); \
                       __builtin_amdgcn_sched_barrier(0); } while (0)
#define WAITLG()  do { asm volatile("s_waitcnt lgkmcnt(0)" ::: "memory"); \
                       __builtin_amdgcn_sched_barrier(0); } while (0)

__device__ __forceinline__ unsigned short f2bf(float f) {
    return __builtin_bit_cast(unsigned short, __float2bfloat16(f));
}

__device__ __forceinline__ short8 cvt8(const float4& a, const float4& b) {
    __hip_bfloat162 p0 = __float22bfloat162_rn(make_float2(a.x, a.y));
    __hip_bfloat162 p1 = __float22bfloat162_rn(make_float2(a.z, a.w));
    __hip_bfloat162 p2 = __float22bfloat162_rn(make_float2(b.x, b.y));
    __hip_bfloat162 p3 = __float22bfloat162_rn(make_float2(b.z, b.w));
    ushort2 u0, u1, u2, u3;
    __builtin_memcpy(&u0, &p0, 4);
    __builtin_memcpy(&u1, &p1, 4);
    __builtin_memcpy(&u2, &p2, 4);
    __builtin_memcpy(&u3, &p3, 4);
    short8 r;
    r[0] = (short)u0.x; r[1] = (short)u0.y;
    r[2] = (short)u1.x; r[3] = (short)u1.y;
    r[4] = (short)u2.x; r[5] = (short)u2.y;
    r[6] = (short)u3.x; r[7] = (short)u3.y;
    return r;
}

__device__ __forceinline__ short8 zero8() {
    short8 z = {0, 0, 0, 0, 0, 0, 0, 0};
    return z;
}

__device__ __forceinline__ void gload_lds16(const float* g, void* l) {
    auto gp = (const __attribute__((address_space(1))) void*)g;
    auto lp = (__attribute__((address_space(3))) void*)l;
    __builtin_amdgcn_global_load_lds(gp, lp, 16, 0, 0);
}

// Per-channel complex scale: sc = nm*cos(atan(a)), ss = nm*sin(atan(a))
__global__ void scale_kernel(const float* __restrict__ wm,
                             const float* __restrict__ wa,
                             float* __restrict__ ws, int C, float batchf) {
    int c = threadIdx.x;
    if (c >= C) return;
    float m = -1e30f;
    for (int i = 0; i < C; ++i) m = fmaxf(m, wm[i]);
    float s = 0.f;
    for (int i = 0; i < C; ++i) s += expf(wm[i] - m);
    float nm = batchf * expf(wm[c] - m) / s;
    float a = wa[c];
    float inv = rsqrtf(1.f + a * a);
    ws[2 * c]     = nm * inv;       // sc
    ws[2 * c + 1] = nm * a * inv;   // ss
}

__global__ __launch_bounds__(THREADS, 3)
void mf_kernel(const float* __restrict__ x,
               const float* __restrict__ kr,
               const float* __restrict__ ki,
               const float* __restrict__ sc_ss,
               float* __restrict__ out, int interleaved) {
    // per-wave double-buffered fp32 window: 2 x 1280 floats (5 KB), 40 KB total
    __shared__ __align__(16) float lf[WPB][2][1280];

    const int seg = blockIdx.x;            // 8 segments
    const int rg  = blockIdx.y;            // 256 row groups (4 rows)
    const int tid = threadIdx.x;
    const int lane= tid & 63;
    const int wv  = tid >> 6;              // wave 0..3
    const int m   = lane & 31;             // A row / output position-block
    const int kh  = lane >> 5;             // k half (0..1)

    const int row = rg * WPB + wv;         // this wave's row (0..1023)
    const int cw0 = seg * T;               // first tile

    // ---- B fragments (k-Toeplitz): B_d[p][n] = k[p-n], lane: n=m, p=16d+8*kh+e
    short8 br[10], bi[10];
    #pragma unroll
    for (int d = 0; d < 10; ++d) {
        #pragma unroll
        for (int e = 0; e < 8; ++e) {
            int idx = 16 * d + 8 * kh + e - m;
            bool ok = (idx >= 0) && (idx < Kc);
            br[d][e] = (short)f2bf(ok ? kr[idx] : 0.f);
            bi[d][e] = (short)f2bf(ok ? ki[idx] : 0.f);
        }
    }

    const int ch = row & (Cc - 1);
    const float scv = sc_ss[2 * ch];
    const float ssv = sc_ss[2 * ch + 1];

    const float* __restrict__ xrow = x + (size_t)row * Lc;

    // swizzled granule for this lane's DMA source (involution; preserves
    // 128-B-group membership -> full coalescing per instruction)
    const int gsw = lane ^ ((lane >> 3) & 7);

    auto DMA = [&](int cw, int buf) {
        const int s0f = cw * TILE - 64;
        #pragma unroll
        for (int t = 0; t < 5; ++t) {
            int src = s0f + 256 * t + 4 * gsw;
            src = min(max(src, 0), Lc - 4);    // edge clamp (no-op interior)
            gload_lds16(xrow + src, (char*)&lf[wv][buf][0] + 1024 * t);
        }
    };

    // ---- prologue ----
    DMA(cw0, 0);
    DMA(cw0 + 1, 1);

    const int G0 = 8 * m + 2 * kh;         // granule base for A-frag reads

    #pragma unroll
    for (int c = 0; c < T; ++c) {
        const int cw  = cw0 + c;
        const int buf = c & 1;

        // wait tile c's 5 DMA (exact counted; stores/DMA younger)
        if (c == 0)      WAITVM(5);
        else if (c == 1) WAITVM(21);
        else if (c == 2) WAITVM(37);
        else             WAITVM(32);

        const float* lwp = &lf[wv][buf][0];
        const bool e_lo = (cw == 0);
        const bool e_hi = (cw == LASTTILE);

        floatx16 cr = {};
        floatx16 ci = {};
        #pragma unroll
        for (int d = 0; d < 10; ++d) {
            const int Ga = G0 + 4 * d;       // first granule of fragment
            const int Gb = Ga + 1;           // second granule
            const int la = (Ga & 63) ^ ((Ga >> 3) & 7);
            const int lb = (Gb & 63) ^ ((Gb >> 3) & 7);   // = la ^ 1
            const float* pa = lwp + ((Ga >> 6) << 8) + 4 * la;
            const float* pb = lwp + ((Gb >> 6) << 8) + 4 * lb;
            float4 fa = *reinterpret_cast<const float4*>(pa);
            float4 fb = *reinterpret_cast<const float4*>(pb);
            short8 a = cvt8(fa, fb);
            // edge zeroing: source pos = cw*1024 - 64 + 32m + (16d+8kh+e)
            if (e_lo && ((m == 0 && d < 4) || (m == 1 && d < 2))) a = zero8();
            if (e_hi && ((m == 31 && d >= 6) || (m == 30 && d >= 8))) a = zero8();
            cr = __builtin_amdgcn_mfma_f32_32x32x16_bf16(a, br[d], cr, 0, 0, 0);
            ci = __builtin_amdgcn_mfma_f32_32x32x16_bf16(a, bi[d], ci, 0, 0, 0);
        }

        // buffer's data consumed (in regs); fence then reuse for tile c+2
        WAITLG();
        if (c + 2 < T) DMA(cw0 + c + 2, buf);

        // D[mm][n]: n = lane&31, mm = (r&3) + 8*(r>>2) + 4*kh (verified C map)
        // output pos q = 32*mm + n
        if (!interleaved) {
            float* op = out + (size_t)row * Lc + cw * TILE + 128 * kh + m;
            #pragma unroll
            for (int r = 0; r < 16; ++r) {
                const int off = 32 * (r & 3) + 256 * (r >> 2);
                op[off] = scv * cr[r] - ssv * ci[r];
            }
        } else {
            float2* op = reinterpret_cast<float2*>(out) +
                         ((size_t)row * Lc + cw * TILE + 128 * kh + m);
            #pragma unroll
            for (int r = 0; r < 16; ++r) {
                const int off = 32 * (r & 3) + 256 * (r >> 2);
                op[off] = make_float2(scv * cr[r] - ssv * ci[r],
                                      -scv * ci[r] - ssv * cr[r]);
            }
        }
    }
}

extern "C" void kernel_launch(void* const* d_in, const int* in_sizes, int n_in,
                              void* d_out, int out_size, void* d_ws, size_t ws_size,
                              hipStream_t stream) {
    const float* x  = (const float*)d_in[0];
    const float* wm = (const float*)d_in[1];
    const float* wa = (const float*)d_in[2];
    const float* kr = (const float*)d_in[3];
    const float* ki = (const float*)d_in[4];
    float* out = (float*)d_out;
    float* ws  = (float*)d_ws;

    const int C = in_sizes[1];  // 128
    const long long N = (long long)Bc * Cc * Lc;
    const int interleaved = (out_size == 2 * N) ? 1 : 0;

    hipLaunchKernelGGL(scale_kernel, dim3(1), dim3(C), 0, stream,
                       wm, wa, ws, C, (float)Bc);

    dim3 grid(NSEG, (Bc * Cc) / WPB);   // 8 x 256 = 2048 blocks
    hipLaunchKernelGGL(mf_kernel, grid, dim3(THREADS), 0, stream,
                       x, kr, ki, ws, out, interleaved);
}

// Round 20
// 107.349 us; speedup vs baseline: 2.0077x; 1.0070x over previous
//
#include <hip/hip_runtime.h>
#include <hip/hip_bf16.h>
#include <math.h>

// OptimizeSNR R20: Toeplitz-swap MFMA with ds_bpermute fragment redistribution.
//   out[t0+16m+n] = sum_p A[m,p]*B[p,n]
//   A[m,p] = x[t0-64+16m+p]: window (512 floats) lives in wave REGISTERS
//            (lane L holds x[w0+8L..+8)); fragment (fn,fh,d) = the 4 bf16
//            dwords of source lane (2fn+fh+4d) -> 4 ds_bpermute, shared addr.
//   B[p,n] = k[p-n] (k-Toeplitz, VGPRs).
//   Zero barriers; depth-2 counted-vmcnt load prefetch; 4KB LDS store bounce
//   -> one contiguous 1KB/wave dwordx4 store per tile.
constexpr int Bc = 8, Cc = 128, Lc = 32768, Kc = 129;

constexpr int MLEN = 256;              // outputs per tile
constexpr int T    = 16;               // tiles per wave
constexpr int NSEG = Lc / (MLEN * T);  // 8
constexpr int WPB  = 4;
constexpr int THREADS = 64 * WPB;      // 256
constexpr int LASTCW  = Lc / MLEN - 1; // 127

typedef __attribute__((ext_vector_type(8))) short short8;
typedef __attribute__((ext_vector_type(4))) int   intx4;
typedef __attribute__((ext_vector_type(4))) float floatx4;

#define WAITVM(N) do { asm volatile("s_waitcnt vmcnt(" #N ")" ::: "memory"); \
                       __builtin_amdgcn_sched_barrier(0); } while (0)

__device__ __forceinline__ unsigned short f2bf(float f) {
    return __builtin_bit_cast(unsigned short, __float2bfloat16(f));
}

__device__ __forceinline__ int cvt2(float lo, float hi) {
    __hip_bfloat162 p = __float22bfloat162_rn(make_float2(lo, hi));
    int r;
    __builtin_memcpy(&r, &p, 4);
    return r;
}

// Per-channel complex scale: sc = nm*cos(atan(a)), ss = nm*sin(atan(a))
__global__ void scale_kernel(const float* __restrict__ wm,
                             const float* __restrict__ wa,
                             float* __restrict__ ws, int C, float batchf) {
    int c = threadIdx.x;
    if (c >= C) return;
    float m = -1e30f;
    for (int i = 0; i < C; ++i) m = fmaxf(m, wm[i]);
    float s = 0.f;
    for (int i = 0; i < C; ++i) s += expf(wm[i] - m);
    float nm = batchf * expf(wm[c] - m) / s;
    float a = wa[c];
    float inv = rsqrtf(1.f + a * a);
    ws[2 * c]     = nm * inv;       // sc
    ws[2 * c + 1] = nm * a * inv;   // ss
}

__global__ __launch_bounds__(THREADS, 5)
void mf_kernel(const float* __restrict__ x,
               const float* __restrict__ kr,
               const float* __restrict__ ki,
               const float* __restrict__ sc_ss,
               float* __restrict__ out, int interleaved) {
    __shared__ __align__(16) float lo[WPB][256];   // 4 KB store bounce

    const int seg = blockIdx.x;            // 8 segments
    const int rg  = blockIdx.y;            // 256 row groups (4 rows)
    const int tid = threadIdx.x;
    const int lane= tid & 63;
    const int wv  = tid >> 6;
    const int fh  = lane >> 4;             // 0..3
    const int fn  = lane & 15;             // 0..15

    const int row = rg * WPB + wv;         // 0..1023
    const int cw0 = seg * T;

    // ---- B fragments (k-Toeplitz): B_d[kl][n] = k[32d+kl-n]; lane: n=fn, kl=8*fh+e
    short8 br[5], bi[5];
    #pragma unroll
    for (int d = 0; d < 5; ++d) {
        #pragma unroll
        for (int e = 0; e < 8; ++e) {
            int idx = 32 * d + 8 * fh + e - fn;
            bool ok = (idx >= 0) && (idx < Kc);
            br[d][e] = (short)f2bf(ok ? kr[idx] : 0.f);
            bi[d][e] = (short)f2bf(ok ? ki[idx] : 0.f);
        }
    }

    const int ch = row & (Cc - 1);
    const float scv = sc_ss[2 * ch];
    const float ssv = sc_ss[2 * ch + 1];

    const float* __restrict__ xrow = x + (size_t)row * Lc;

    // bpermute addresses: source lane for fragment d = 2*fn + fh + 4*d
    int baddr[5];
    #pragma unroll
    for (int d = 0; d < 5; ++d) baddr[d] = 4 * (2 * fn + fh + 4 * d);

    float4 F[2][2];
    auto ISSUE = [&](int cw, int buf0) {
        int g = cw * MLEN - 64 + 8 * lane;
        g = min(max(g, 0), Lc - 8);        // no-op interior, clamps edges
        F[buf0][0] = *reinterpret_cast<const float4*>(xrow + g);
        F[buf0][1] = *reinterpret_cast<const float4*>(xrow + g + 4);
    };

    // ---- prologue ----
    ISSUE(cw0, 0);
    ISSUE(cw0 + 1, 1);

    #pragma unroll
    for (int c = 0; c < T; ++c) {
        const int cw  = cw0 + c;
        const int buf = c & 1;

        // wait tile c's 2 loads (exact counted: younger = next loads + prev store)
        if (c == 0)          WAITVM(2);
        else if (c == T - 1) WAITVM(1);
        else                 WAITVM(3);

        // window -> 4 bf16 dwords per lane
        const float4 fa = F[buf][0], fb = F[buf][1];
        int b0 = cvt2(fa.x, fa.y);
        int b1 = cvt2(fa.z, fa.w);
        int b2 = cvt2(fb.x, fb.y);
        int b3 = cvt2(fb.z, fb.w);

        // F[buf] dead -> issue tile c+2's loads now
        if (c + 2 < T) ISSUE(cw + 2, buf);

        floatx4 cr = {0.f, 0.f, 0.f, 0.f};
        floatx4 ci = {0.f, 0.f, 0.f, 0.f};
        #pragma unroll
        for (int d = 0; d < 5; ++d) {
            intx4 w;
            w.x = __builtin_amdgcn_ds_bpermute(baddr[d], b0);
            w.y = __builtin_amdgcn_ds_bpermute(baddr[d], b1);
            w.z = __builtin_amdgcn_ds_bpermute(baddr[d], b2);
            w.w = __builtin_amdgcn_ds_bpermute(baddr[d], b3);
            short8 a = __builtin_bit_cast(short8, w);
            // edge zeroing: window pos of frag = 8*srclane; invalid iff clamped
            if (cw == 0) {
                if (2 * fn + fh + 4 * d < 8) a = short8{0,0,0,0,0,0,0,0};
            } else if (cw == LASTCW) {
                if (2 * fn + fh + 4 * d >= 40) a = short8{0,0,0,0,0,0,0,0};
            }
            cr = __builtin_amdgcn_mfma_f32_16x16x32_bf16(a, br[d], cr, 0, 0, 0);
            ci = __builtin_amdgcn_mfma_f32_16x16x32_bf16(a, bi[d], ci, 0, 0, 0);
        }

        // epilogue: D[m=4*fh+r][n=fn], pos = cw*256 + 64*fh + 16*r + fn.
        if (!interleaved) {
            const int bb = 64 * fh + fn;
            lo[wv][bb]      = scv * cr[0] - ssv * ci[0];
            lo[wv][bb + 16] = scv * cr[1] - ssv * ci[1];
            lo[wv][bb + 32] = scv * cr[2] - ssv * ci[2];
            lo[wv][bb + 48] = scv * cr[3] - ssv * ci[3];
            float4 ov = *reinterpret_cast<const float4*>(&lo[wv][4 * lane]);
            *reinterpret_cast<float4*>(out + (size_t)row * Lc + cw * MLEN + 4 * lane) = ov;
        } else {
            float2* op = reinterpret_cast<float2*>(out) +
                         ((size_t)row * Lc + cw * MLEN + 64 * fh + fn);
            #pragma unroll
            for (int r = 0; r < 4; ++r)
                op[16 * r] = make_float2(scv * cr[r] - ssv * ci[r],
                                         -scv * ci[r] - ssv * cr[r]);
        }
    }
}

extern "C" void kernel_launch(void* const* d_in, const int* in_sizes, int n_in,
                              void* d_out, int out_size, void* d_ws, size_t ws_size,
                              hipStream_t stream) {
    const float* x  = (const float*)d_in[0];
    const float* wm = (const float*)d_in[1];
    const float* wa = (const float*)d_in[2];
    const float* kr = (const float*)d_in[3];
    const float* ki = (const float*)d_in[4];
    float* out = (float*)d_out;
    float* ws  = (float*)d_ws;

    const int C = in_sizes[1];  // 128
    const long long N = (long long)Bc * Cc * Lc;
    const int interleaved = (out_size == 2 * N) ? 1 : 0;

    hipLaunchKernelGGL(scale_kernel, dim3(1), dim3(C), 0, stream,
                       wm, wa, ws, C, (float)Bc);

    dim3 grid(NSEG, (Bc * Cc) / WPB);   // 8 x 256 = 2048 blocks
    hipLaunchKernelGGL(mf_kernel, grid, dim3(THREADS), 0, stream,
                       x, kr, ki, ws, out, interleaved);
}

// Round 21
// 70.892 us; speedup vs baseline: 3.0401x; 1.5142x over previous
//
#include <hip/hip_runtime.h>
#include <hip/hip_bf16.h>
#include <math.h>

// OptimizeSNR R21: Toeplitz-swap MFMA, single-LDS-hop window.
//   out[t0+16m+n] = sum_p A[m,p]*B[p,n]
//   A[m,p] = x[t0-64+16m+p]: lane L loads x[w0+8L..+8) (2 coalesced dwordx4),
//            cvt to bf16 in-reg, ONE ds_write_b128 -> wave-private 1KB window;
//            fragment (fn,fh,d) = granule 2fn+fh+4d, ONE ds_read_b128 each.
//   B[p,n] = k[p-n] (k-Toeplitz, VGPRs).
//   Zero barriers; depth-2 counted-vmcnt prefetch; R15-style scalar stores.
constexpr int Bc = 8, Cc = 128, Lc = 32768, Kc = 129;

constexpr int MLEN = 256;              // outputs per tile
constexpr int T    = 16;               // tiles per wave
constexpr int NSEG = Lc / (MLEN * T);  // 8
constexpr int WPB  = 4;
constexpr int THREADS = 64 * WPB;      // 256
constexpr int LASTCW  = Lc / MLEN - 1; // 127

typedef __attribute__((ext_vector_type(8))) short short8;
typedef __attribute__((ext_vector_type(4))) float floatx4;

#define WAITVM(N) do { asm volatile("s_waitcnt vmcnt(" #N ")" ::: "memory"); \
                       __builtin_amdgcn_sched_barrier(0); } while (0)

__device__ __forceinline__ unsigned short f2bf(float f) {
    return __builtin_bit_cast(unsigned short, __float2bfloat16(f));
}

__device__ __forceinline__ short8 cvt8(const float4& a, const float4& b) {
    __hip_bfloat162 p0 = __float22bfloat162_rn(make_float2(a.x, a.y));
    __hip_bfloat162 p1 = __float22bfloat162_rn(make_float2(a.z, a.w));
    __hip_bfloat162 p2 = __float22bfloat162_rn(make_float2(b.x, b.y));
    __hip_bfloat162 p3 = __float22bfloat162_rn(make_float2(b.z, b.w));
    ushort2 u0, u1, u2, u3;
    __builtin_memcpy(&u0, &p0, 4);
    __builtin_memcpy(&u1, &p1, 4);
    __builtin_memcpy(&u2, &p2, 4);
    __builtin_memcpy(&u3, &p3, 4);
    short8 r;
    r[0] = (short)u0.x; r[1] = (short)u0.y;
    r[2] = (short)u1.x; r[3] = (short)u1.y;
    r[4] = (short)u2.x; r[5] = (short)u2.y;
    r[6] = (short)u3.x; r[7] = (short)u3.y;
    return r;
}

// Per-channel complex scale: sc = nm*cos(atan(a)), ss = nm*sin(atan(a))
__global__ void scale_kernel(const float* __restrict__ wm,
                             const float* __restrict__ wa,
                             float* __restrict__ ws, int C, float batchf) {
    int c = threadIdx.x;
    if (c >= C) return;
    float m = -1e30f;
    for (int i = 0; i < C; ++i) m = fmaxf(m, wm[i]);
    float s = 0.f;
    for (int i = 0; i < C; ++i) s += expf(wm[i] - m);
    float nm = batchf * expf(wm[c] - m) / s;
    float a = wa[c];
    float inv = rsqrtf(1.f + a * a);
    ws[2 * c]     = nm * inv;       // sc
    ws[2 * c + 1] = nm * a * inv;   // ss
}

__global__ __launch_bounds__(THREADS, 4)
void mf_kernel(const float* __restrict__ x,
               const float* __restrict__ kr,
               const float* __restrict__ ki,
               const float* __restrict__ sc_ss,
               float* __restrict__ out, int interleaved) {
    __shared__ __align__(16) unsigned short lb[WPB][512];   // 4 KB: bf16 windows

    const int seg = blockIdx.x;            // 8 segments
    const int rg  = blockIdx.y;            // 256 row groups (4 rows)
    const int tid = threadIdx.x;
    const int lane= tid & 63;
    const int wv  = tid >> 6;
    const int fh  = lane >> 4;             // 0..3
    const int fn  = lane & 15;             // 0..15

    const int row = rg * WPB + wv;         // 0..1023
    const int cw0 = seg * T;

    // ---- B fragments (k-Toeplitz): B_d[kl][n] = k[32d+kl-n]; lane: n=fn, kl=8*fh+e
    short8 br[5], bi[5];
    #pragma unroll
    for (int d = 0; d < 5; ++d) {
        #pragma unroll
        for (int e = 0; e < 8; ++e) {
            int idx = 32 * d + 8 * fh + e - fn;
            bool ok = (idx >= 0) && (idx < Kc);
            br[d][e] = (short)f2bf(ok ? kr[idx] : 0.f);
            bi[d][e] = (short)f2bf(ok ? ki[idx] : 0.f);
        }
    }

    const int ch = row & (Cc - 1);
    const float scv = sc_ss[2 * ch];
    const float ssv = sc_ss[2 * ch + 1];

    const float* __restrict__ xrow = x + (size_t)row * Lc;

    float4 F[2][2];
    auto ISSUE = [&](int cw, int buf0) {
        int g = cw * MLEN - 64 + 8 * lane;
        g = min(max(g, 0), Lc - 8);        // no-op interior, clamps edges
        F[buf0][0] = *reinterpret_cast<const float4*>(xrow + g);
        F[buf0][1] = *reinterpret_cast<const float4*>(xrow + g + 4);
    };

    // ---- prologue ----
    ISSUE(cw0, 0);
    ISSUE(cw0 + 1, 1);

    #pragma unroll
    for (int c = 0; c < T; ++c) {
        const int cw  = cw0 + c;
        const int buf = c & 1;

        // wait tile c's 2 loads (younger = next tile's 2 loads + prev 4 stores)
        if (c == 0)          WAITVM(2);
        else if (c == T - 1) WAITVM(4);
        else                 WAITVM(6);

        // window -> 8 bf16 (one 16B granule) per lane, single ds_write_b128
        short8 h = cvt8(F[buf][0], F[buf][1]);

        // F[buf] dead -> issue tile c+2's loads now
        if (c + 2 < T) ISSUE(cw + 2, buf);

        *reinterpret_cast<short8*>(&lb[wv][8 * lane]) = h;

        floatx4 cr = {0.f, 0.f, 0.f, 0.f};
        floatx4 ci = {0.f, 0.f, 0.f, 0.f};
        #pragma unroll
        for (int d = 0; d < 5; ++d) {
            // fragment = window shorts [16fn+8fh+32d, +8) = granule 2fn+fh+4d
            short8 a = *reinterpret_cast<const short8*>(
                &lb[wv][16 * fn + 8 * fh + 32 * d]);
            // edge zeroing: granule gg holds garbage iff clamped at load
            if (cw == 0) {
                if (2 * fn + fh + 4 * d < 8) a = short8{0,0,0,0,0,0,0,0};
            } else if (cw == LASTCW) {
                if (2 * fn + fh + 4 * d >= 40) a = short8{0,0,0,0,0,0,0,0};
            }
            cr = __builtin_amdgcn_mfma_f32_16x16x32_bf16(a, br[d], cr, 0, 0, 0);
            ci = __builtin_amdgcn_mfma_f32_16x16x32_bf16(a, bi[d], ci, 0, 0, 0);
        }

        // D[m=4*fh+r][n=fn]; output pos = cw*256 + 64*fh + 16*r + fn  (R15 style)
        if (!interleaved) {
            float* op = out + (size_t)row * Lc + cw * MLEN + 64 * fh + fn;
            #pragma unroll
            for (int r = 0; r < 4; ++r)
                op[16 * r] = scv * cr[r] - ssv * ci[r];
        } else {
            float2* op = reinterpret_cast<float2*>(out) +
                         ((size_t)row * Lc + cw * MLEN + 64 * fh + fn);
            #pragma unroll
            for (int r = 0; r < 4; ++r)
                op[16 * r] = make_float2(scv * cr[r] - ssv * ci[r],
                                         -scv * ci[r] - ssv * cr[r]);
        }
    }
}

extern "C" void kernel_launch(void* const* d_in, const int* in_sizes, int n_in,
                              void* d_out, int out_size, void* d_ws, size_t ws_size,
                              hipStream_t stream) {
    const float* x  = (const float*)d_in[0];
    const float* wm = (const float*)d_in[1];
    const float* wa = (const float*)d_in[2];
    const float* kr = (const float*)d_in[3];
    const float* ki = (const float*)d_in[4];
    float* out = (float*)d_out;
    float* ws  = (float*)d_ws;

    const int C = in_sizes[1];  // 128
    const long long N = (long long)Bc * Cc * Lc;
    const int interleaved = (out_size == 2 * N) ? 1 : 0;

    hipLaunchKernelGGL(scale_kernel, dim3(1), dim3(C), 0, stream,
                       wm, wa, ws, C, (float)Bc);

    dim3 grid(NSEG, (Bc * Cc) / WPB);   // 8 x 256 = 2048 blocks
    hipLaunchKernelGGL(mf_kernel, grid, dim3(THREADS), 0, stream,
                       x, kr, ki, ws, out, interleaved);
}

// Round 22
// 70.155 us; speedup vs baseline: 3.0720x; 1.0105x over previous
//
#include <hip/hip_runtime.h>
#include <hip/hip_bf16.h>
#include <math.h>

// OptimizeSNR R22 = R21 with store-exclusive vmcnt counting.
//   R21's WAITVM(6) steady-state inadvertently waited for global-store acks
//   (stores are vmcnt ops, and draining to 6 includes iter c-2's 4 stores).
//   Corrected: steady vmcnt(10) drains ONLY tile-c's 2 loads.
constexpr int Bc = 8, Cc = 128, Lc = 32768, Kc = 129;

constexpr int MLEN = 256;              // outputs per tile
constexpr int T    = 16;               // tiles per wave
constexpr int NSEG = Lc / (MLEN * T);  // 8
constexpr int WPB  = 4;
constexpr int THREADS = 64 * WPB;      // 256
constexpr int LASTCW  = Lc / MLEN - 1; // 127

typedef __attribute__((ext_vector_type(8))) short short8;
typedef __attribute__((ext_vector_type(4))) float floatx4;

#define WAITVM(N) do { asm volatile("s_waitcnt vmcnt(" #N ")" ::: "memory"); \
                       __builtin_amdgcn_sched_barrier(0); } while (0)

__device__ __forceinline__ unsigned short f2bf(float f) {
    return __builtin_bit_cast(unsigned short, __float2bfloat16(f));
}

__device__ __forceinline__ short8 cvt8(const float4& a, const float4& b) {
    __hip_bfloat162 p0 = __float22bfloat162_rn(make_float2(a.x, a.y));
    __hip_bfloat162 p1 = __float22bfloat162_rn(make_float2(a.z, a.w));
    __hip_bfloat162 p2 = __float22bfloat162_rn(make_float2(b.x, b.y));
    __hip_bfloat162 p3 = __float22bfloat162_rn(make_float2(b.z, b.w));
    ushort2 u0, u1, u2, u3;
    __builtin_memcpy(&u0, &p0, 4);
    __builtin_memcpy(&u1, &p1, 4);
    __builtin_memcpy(&u2, &p2, 4);
    __builtin_memcpy(&u3, &p3, 4);
    short8 r;
    r[0] = (short)u0.x; r[1] = (short)u0.y;
    r[2] = (short)u1.x; r[3] = (short)u1.y;
    r[4] = (short)u2.x; r[5] = (short)u2.y;
    r[6] = (short)u3.x; r[7] = (short)u3.y;
    return r;
}

// Per-channel complex scale: sc = nm*cos(atan(a)), ss = nm*sin(atan(a))
__global__ void scale_kernel(const float* __restrict__ wm,
                             const float* __restrict__ wa,
                             float* __restrict__ ws, int C, float batchf) {
    int c = threadIdx.x;
    if (c >= C) return;
    float m = -1e30f;
    for (int i = 0; i < C; ++i) m = fmaxf(m, wm[i]);
    float s = 0.f;
    for (int i = 0; i < C; ++i) s += expf(wm[i] - m);
    float nm = batchf * expf(wm[c] - m) / s;
    float a = wa[c];
    float inv = rsqrtf(1.f + a * a);
    ws[2 * c]     = nm * inv;       // sc
    ws[2 * c + 1] = nm * a * inv;   // ss
}

__global__ __launch_bounds__(THREADS, 4)
void mf_kernel(const float* __restrict__ x,
               const float* __restrict__ kr,
               const float* __restrict__ ki,
               const float* __restrict__ sc_ss,
               float* __restrict__ out, int interleaved) {
    __shared__ __align__(16) unsigned short lb[WPB][512];   // 4 KB: bf16 windows

    const int seg = blockIdx.x;            // 8 segments
    const int rg  = blockIdx.y;            // 256 row groups (4 rows)
    const int tid = threadIdx.x;
    const int lane= tid & 63;
    const int wv  = tid >> 6;
    const int fh  = lane >> 4;             // 0..3
    const int fn  = lane & 15;             // 0..15

    const int row = rg * WPB + wv;         // 0..1023
    const int cw0 = seg * T;

    // ---- B fragments (k-Toeplitz): B_d[kl][n] = k[32d+kl-n]; lane: n=fn, kl=8*fh+e
    short8 br[5], bi[5];
    #pragma unroll
    for (int d = 0; d < 5; ++d) {
        #pragma unroll
        for (int e = 0; e < 8; ++e) {
            int idx = 32 * d + 8 * fh + e - fn;
            bool ok = (idx >= 0) && (idx < Kc);
            br[d][e] = (short)f2bf(ok ? kr[idx] : 0.f);
            bi[d][e] = (short)f2bf(ok ? ki[idx] : 0.f);
        }
    }

    const int ch = row & (Cc - 1);
    const float scv = sc_ss[2 * ch];
    const float ssv = sc_ss[2 * ch + 1];

    const float* __restrict__ xrow = x + (size_t)row * Lc;

    float4 F[2][2];
    auto ISSUE = [&](int cw, int buf0) {
        int g = cw * MLEN - 64 + 8 * lane;
        g = min(max(g, 0), Lc - 8);        // no-op interior, clamps edges
        F[buf0][0] = *reinterpret_cast<const float4*>(xrow + g);
        F[buf0][1] = *reinterpret_cast<const float4*>(xrow + g + 4);
    };

    // ---- prologue ----
    ISSUE(cw0, 0);
    ISSUE(cw0 + 1, 1);

    #pragma unroll
    for (int c = 0; c < T; ++c) {
        const int cw  = cw0 + c;
        const int buf = c & 1;

        // Drain ONLY tile-c's 2 loads; never wait on store acks.
        // In-flight at this point (steady): tile-c loads [2] + iter c-2
        // stores [4] + iter c-1 loads [2] + iter c-1 stores [4] = 12.
        if (c == 0)          WAITVM(2);
        else if (c == 1)     WAITVM(6);
        else if (c == T - 1) WAITVM(8);
        else                 WAITVM(10);

        // window -> 8 bf16 (one 16B granule) per lane, single ds_write_b128
        short8 h = cvt8(F[buf][0], F[buf][1]);

        // F[buf] dead -> issue tile c+2's loads now
        if (c + 2 < T) ISSUE(cw + 2, buf);

        *reinterpret_cast<short8*>(&lb[wv][8 * lane]) = h;

        floatx4 cr = {0.f, 0.f, 0.f, 0.f};
        floatx4 ci = {0.f, 0.f, 0.f, 0.f};
        #pragma unroll
        for (int d = 0; d < 5; ++d) {
            // fragment = window shorts [16fn+8fh+32d, +8) = granule 2fn+fh+4d
            short8 a = *reinterpret_cast<const short8*>(
                &lb[wv][16 * fn + 8 * fh + 32 * d]);
            // edge zeroing: granule gg holds garbage iff clamped at load
            if (cw == 0) {
                if (2 * fn + fh + 4 * d < 8) a = short8{0,0,0,0,0,0,0,0};
            } else if (cw == LASTCW) {
                if (2 * fn + fh + 4 * d >= 40) a = short8{0,0,0,0,0,0,0,0};
            }
            cr = __builtin_amdgcn_mfma_f32_16x16x32_bf16(a, br[d], cr, 0, 0, 0);
            ci = __builtin_amdgcn_mfma_f32_16x16x32_bf16(a, bi[d], ci, 0, 0, 0);
        }

        // D[m=4*fh+r][n=fn]; output pos = cw*256 + 64*fh + 16*r + fn
        if (!interleaved) {
            float* op = out + (size_t)row * Lc + cw * MLEN + 64 * fh + fn;
            #pragma unroll
            for (int r = 0; r < 4; ++r)
                op[16 * r] = scv * cr[r] - ssv * ci[r];
        } else {
            float2* op = reinterpret_cast<float2*>(out) +
                         ((size_t)row * Lc + cw * MLEN + 64 * fh + fn);
            #pragma unroll
            for (int r = 0; r < 4; ++r)
                op[16 * r] = make_float2(scv * cr[r] - ssv * ci[r],
                                         -scv * ci[r] - ssv * cr[r]);
        }
    }
}

extern "C" void kernel_launch(void* const* d_in, const int* in_sizes, int n_in,
                              void* d_out, int out_size, void* d_ws, size_t ws_size,
                              hipStream_t stream) {
    const float* x  = (const float*)d_in[0];
    const float* wm = (const float*)d_in[1];
    const float* wa = (const float*)d_in[2];
    const float* kr = (const float*)d_in[3];
    const float* ki = (const float*)d_in[4];
    float* out = (float*)d_out;
    float* ws  = (float*)d_ws;

    const int C = in_sizes[1];  // 128
    const long long N = (long long)Bc * Cc * Lc;
    const int interleaved = (out_size == 2 * N) ? 1 : 0;

    hipLaunchKernelGGL(scale_kernel, dim3(1), dim3(C), 0, stream,
                       wm, wa, ws, C, (float)Bc);

    dim3 grid(NSEG, (Bc * Cc) / WPB);   // 8 x 256 = 2048 blocks
    hipLaunchKernelGGL(mf_kernel, grid, dim3(THREADS), 0, stream,
                       x, kr, ki, ws, out, interleaved);
}